// Round 1
// baseline (358.162 us; speedup 1.0000x reference)
//
#include <hip/hip_runtime.h>
#include <hip/hip_bf16.h>

// Event-camera simulator: per-pixel independent scan over T frames.
// One thread per pixel, fully unrolled t-loop.

namespace {
constexpr int Bc = 4, Hc = 480, Wc = 640, Tc = 32;
constexpr int HW  = Hc * Wc;     // 307200
constexpr int BHW = Bc * HW;     // 1228800
}

__device__ __forceinline__ float rfl(float x) {
    // wave-uniform value -> SGPR (b is uniform per wave: 64 | HW)
    return __uint_as_float(__builtin_amdgcn_readfirstlane(__float_as_uint(x)));
}

__global__ __launch_bounds__(256) void event_sim_kernel(
    const float* __restrict__ log_images,    // (H, W, B*T)
    const float* __restrict__ image_ts,      // (B, T)
    const float* __restrict__ first_times,   // (B,)
    const float* __restrict__ thresholds,    // (2, B, H, W)
    const float* __restrict__ log_states,    // (B, H, W)
    const float* __restrict__ timestamps,    // (B, H, W)
    const float* __restrict__ prev_image_ts, // (B,)
    const float* __restrict__ refractory,    // (B,)
    const float* __restrict__ leak_rates,    // (B,)
    const float* __restrict__ shot_rates,    // (B,)
    const float* __restrict__ threshold_mus, // (B, 2)
    const float* __restrict__ rng,           // (T, B, H, W)
    float* __restrict__ out)                 // (B, H, W)
{
#pragma clang fp contract(off)
    const int idx = blockIdx.x * 256 + threadIdx.x;
    if (idx >= BHW) return;
    const int b = idx / HW;
    const int p = idx - b * HW;   // h*W + w

    // ---- frames: per-pixel T=32 floats are contiguous (128 B) ----
    const float4* fr4 = reinterpret_cast<const float4*>(log_images)
                        + ((size_t)p * Bc + b) * (Tc / 4);
    float fs[Tc];
#pragma unroll
    for (int i = 0; i < Tc / 4; ++i) {
        float4 v = fr4[i];
        fs[4*i+0] = v.x; fs[4*i+1] = v.y; fs[4*i+2] = v.z; fs[4*i+3] = v.w;
    }

    // ---- per-b timestamps (wave-uniform -> SGPRs) ----
    const float4* ts4 = reinterpret_cast<const float4*>(image_ts) + b * (Tc / 4);
    float tss[Tc];
#pragma unroll
    for (int i = 0; i < Tc / 4; ++i) {
        float4 v = ts4[i];
        tss[4*i+0] = rfl(v.x); tss[4*i+1] = rfl(v.y);
        tss[4*i+2] = rfl(v.z); tss[4*i+3] = rfl(v.w);
    }

    const float ref   = rfl(refractory[b]);
    const float leak  = rfl(leak_rates[b]);
    const float shot  = rfl(shot_rates[b]);
    const float mu_on = rfl(threshold_mus[2*b + 1]);
    const bool  ft    = rfl(first_times[b]) > 0.0f;
    const float pv    = rfl(prev_image_ts[b]);

    const float th_off = thresholds[idx];          // (0,b,h,w)
    const float th_on  = thresholds[BHW + idx];    // (1,b,h,w)

    float state   = ft ? fs[0]  : log_states[idx];
    const float ts0 = ft ? tss[0] : pv;
    float last    = ft ? (ts0 - ref) : timestamps[idx];
    float counts  = 0.0f;
    float ts_prev = ts0;

    const float* rng_base = rng + idx;

#pragma unroll
    for (int t = 1; t < Tc; ++t) {
        const float ts_t = tss[t];
        const float u    = rng_base[(size_t)t * BHW];   // coalesced
        const float dt   = ts_t - ts_prev;

        // state leak: state - ((leak*dt)*mu_on)  (reference association)
        state = state - ((leak * dt) * mu_on);

        const float diff = fs[t] - state;
        const bool  pos  = diff >= 0.0f;
        const float th   = pos ? th_on : th_off;
        float n = floorf(fabsf(diff) / th);            // IEEE div + exact floor
        const bool okb = (ts_t - last) >= ref;
        n = okb ? n : 0.0f;
        const float pn = pos ? n : -n;                 // pol * n
        state  = state + (pn * th);                    // (pol*n)*th
        counts = counts + pn;
        last   = (n > 0.0f) ? ts_t : last;

        // shot noise (uses UPDATED last, per reference ordering)
        const float pshot  = shot * dt;
        const bool  is_shot = (u < pshot) && ((ts_t - last) >= ref);
        const float pol_s  = (u < (0.5f * pshot)) ? 1.0f : -1.0f;
        counts = is_shot ? (counts + pol_s) : counts;
        last   = is_shot ? ts_t : last;

        ts_prev = ts_t;
    }

    out[idx] = counts;
}

extern "C" void kernel_launch(void* const* d_in, const int* in_sizes, int n_in,
                              void* d_out, int out_size, void* d_ws, size_t ws_size,
                              hipStream_t stream) {
    const float* log_images    = (const float*)d_in[0];
    // d_in[1] = video_len (int64) — unused by the reference computation
    const float* image_ts      = (const float*)d_in[2];
    const float* first_times   = (const float*)d_in[3];
    const float* thresholds    = (const float*)d_in[4];
    const float* log_states    = (const float*)d_in[5];
    const float* timestamps    = (const float*)d_in[6];
    const float* prev_image_ts = (const float*)d_in[7];
    const float* refractory    = (const float*)d_in[8];
    const float* leak_rates    = (const float*)d_in[9];
    const float* shot_rates    = (const float*)d_in[10];
    const float* threshold_mus = (const float*)d_in[11];
    const float* rng           = (const float*)d_in[12];
    float* out = (float*)d_out;

    dim3 grid((BHW + 255) / 256);
    dim3 block(256);
    hipLaunchKernelGGL(event_sim_kernel, grid, block, 0, stream,
                       log_images, image_ts, first_times, thresholds,
                       log_states, timestamps, prev_image_ts, refractory,
                       leak_rates, shot_rates, threshold_mus, rng, out);
}